// Round 1
// 78.162 us; speedup vs baseline: 1.0222x; 1.0222x over previous
//
#include <hip/hip_runtime.h>
#include <math.h>

#define D_DIM 128
#define K_DIM 64
#define R_DIM 8
#define B_DIM 8192
#define XSTR  264        // ushort per staged X row (256 data + 8 pad)

// ws layout (new, compact T):
//   T  : bf16, per kg (4 of them) 40 tiles of [16 kl][32 pos] ushort:
//        tiles 0..35  = y-part   : tile = chunk*9 + cc  (chunk 0..3, cc 0..8)
//                       cc 0..7 = W/sqrt2, cc 8 = h'
//        tiles 36..39 = y^2-part : tile = 36 + chunk    (-0.5*s_inv)
//        per-kg size 40*512 = 20480 ushort; total 81920 ushort = 40960 floats
//   c0 : float [K] at 40960
#define WS_C0F   40960

typedef __bf16 bf16x8 __attribute__((ext_vector_type(8)));
typedef float  f32x4  __attribute__((ext_vector_type(4)));

static __device__ inline unsigned short f2bf(float f) {
  union { float f; unsigned int u; } v; v.f = f;
  unsigned int u = v.u;
  unsigned int lsb = (u >> 16) & 1;
  u += 0x7fffu + lsb;                 // round-to-nearest-even
  return (unsigned short)(u >> 16);
}

// ---------------------------------------------------------------------------
// Per-k precompute. Grid = K blocks, 128 threads. Same math as before; only
// the T store layout changed (compact 40-tile layout, no zero tiles).
// ---------------------------------------------------------------------------
__global__ __launch_bounds__(128) void precomp_kernel(
    const float* __restrict__ m, const float* __restrict__ delta,
    const float* __restrict__ U, const float* __restrict__ lar,
    float* __restrict__ ws) {
  const int k = blockIdx.x;
  const int d = threadIdx.x;  // 0..127

  __shared__ float U_l[D_DIM][R_DIM];
  __shared__ float V_l[D_DIM][R_DIM];
  __shared__ float W_l[D_DIM][R_DIM];
  __shared__ float m_l[D_DIM];
  __shared__ float red[64];
  __shared__ float Linv_s[R_DIM][R_DIM];
  __shared__ float q_s[R_DIM];
  __shared__ float c0_s[1];
  __shared__ float redA[D_DIM], redB[D_DIM], redC[D_DIM];

  const float dl    = delta[k * D_DIM + d];
  const float s_inv = expf(-dl);
  const float mv    = m[k * D_DIM + d];
  m_l[d] = mv;
  const float* Up = U + (size_t)(k * D_DIM + d) * R_DIM;
#pragma unroll
  for (int r = 0; r < R_DIM; ++r) {
    float u = Up[r];
    U_l[d][r] = u;
    V_l[d][r] = u * s_inv;
  }
  redA[d] = dl;
  redB[d] = mv * mv * s_inv;
  redC[d] = (d < K_DIM) ? lar[d] : 0.f;
  __syncthreads();

  if (d < 64) {
    const int r = d >> 3, s = d & 7;
    float acc = (r == s) ? 1.0f : 0.0f;
#pragma unroll 8
    for (int dd = 0; dd < D_DIM; ++dd) acc += U_l[dd][r] * V_l[dd][s];
    red[d] = acc;
  }
  __syncthreads();

  for (int off = 64; off > 0; off >>= 1) {
    if (d < off) {
      redA[d] += redA[d + off];
      redB[d] += redB[d + off];
      redC[d] += redC[d + off];
    }
    __syncthreads();
  }

  if (d == 0) {
    float Lm[8][8];
#pragma unroll
    for (int i = 0; i < 8; ++i) {
#pragma unroll
      for (int j = 0; j < 8; ++j) {
        if (j > i) continue;
        float sum = red[i * 8 + j];
#pragma unroll
        for (int p = 0; p < 8; ++p)
          if (p < j) sum -= Lm[i][p] * Lm[j][p];
        if (i == j) Lm[i][i] = sqrtf(sum);
        else        Lm[i][j] = sum / Lm[j][j];
      }
    }
    float ld = 0.f;
#pragma unroll
    for (int i = 0; i < 8; ++i) ld += logf(Lm[i][i]);

    float Li[8][8];
#pragma unroll
    for (int i = 0; i < 8; ++i)
#pragma unroll
      for (int j = 0; j < 8; ++j) Li[i][j] = 0.f;
#pragma unroll
    for (int j = 0; j < 8; ++j) {
      Li[j][j] = 1.0f / Lm[j][j];
#pragma unroll
      for (int i = 0; i < 8; ++i) {
        if (i <= j) continue;
        float sum = 0.f;
#pragma unroll
        for (int p = 0; p < 8; ++p)
          if (p >= j && p < i) sum += Lm[i][p] * Li[p][j];
        Li[i][j] = -sum / Lm[i][i];
      }
    }
#pragma unroll
    for (int i = 0; i < 8; ++i)
#pragma unroll
      for (int j = 0; j < 8; ++j) Linv_s[i][j] = Li[i][j];

    const float mean = redC[0] * (1.0f / K_DIM);
    const float log_alpha = lar[k] - mean;       // /eps, eps=1
    const float logdetS = redA[0] + 2.0f * ld;
    const float LOG2PI = 1.8378770664093453f;
    const float log_norm = 0.5f * ((float)D_DIM * LOG2PI + logdetS);
    c0_s[0] = log_alpha - log_norm - 0.5f * redB[0];
  }
  __syncthreads();

  float Wr[R_DIM];
#pragma unroll
  for (int r = 0; r < R_DIM; ++r) {
    float acc = 0.f;
#pragma unroll
    for (int s2 = 0; s2 < R_DIM; ++s2)
      if (s2 <= r) acc += V_l[d][s2] * Linv_s[r][s2];
    Wr[r] = acc;
    W_l[d][r] = acc;
  }
  __syncthreads();

  if (d < R_DIM) {
    float acc = 0.f;
#pragma unroll 8
    for (int dd = 0; dd < D_DIM; ++dd) acc += W_l[dd][d] * m_l[dd];
    q_s[d] = acc;
  }
  __syncthreads();

  float hp = mv * s_inv;
#pragma unroll
  for (int r = 0; r < R_DIM; ++r) hp -= q_s[r] * Wr[r];

  const float INV_SQRT2 = 0.70710678118654752f;
  unsigned short* T = (unsigned short*)ws;
  const int kg = k >> 4, kl = k & 15;
  const int chunk = d >> 5, pos = d & 31;
  const size_t kgbase = (size_t)kg * 20480;
  // y-part tiles: tile = chunk*9 + cc, each tile [16 kl][32 pos]
  const size_t by = kgbase + ((size_t)(chunk * 9) * 16 + kl) * 32 + pos;
#pragma unroll
  for (int cc = 0; cc < 8; ++cc)
    T[by + (size_t)cc * 512] = f2bf(Wr[cc] * INV_SQRT2);
  T[by + 8 * 512] = f2bf(hp);
  // y^2 diag tile: tile = 36 + chunk
  const size_t bq = kgbase + ((size_t)(36 + chunk) * 16 + kl) * 32 + pos;
  T[bq] = f2bf(-0.5f * s_inv);

  if (d == 0) {
    float qq = 0.f;
#pragma unroll
    for (int r = 0; r < R_DIM; ++r) qq += q_s[r] * q_s[r];
    ws[WS_C0F + k] = c0_s[0] + 0.5f * qq;   // c0' = c0 + 0.5*||q||^2
  }
}

// ---------------------------------------------------------------------------
// Fused MFMA kernel, barrier-free main loop. T (160 KB total, 40 KB per kg)
// is L2-resident (read by all 512 blocks) -> no LDS staging: each wave loads
// its B-fragments directly to VGPRs via coalesced 1KB global loads. Only one
// __syncthreads (after the X bf16 conversion) before the epilogue. Zero
// y^2-part padding tiles eliminated: 40 MFMAs/wave instead of 72.
// LDS = sX (8.4 KB) + vals2 (4.2 KB) -> occupancy no longer LDS-capped.
// Grid = 512 blocks x 256 threads (4 waves, wave = one kg).
// ---------------------------------------------------------------------------
__global__ __launch_bounds__(256) void logz_full(
    const float* __restrict__ y, const float* __restrict__ ws,
    float* __restrict__ out) {
  __shared__ __align__(16) unsigned short sX[16 * XSTR];        // 8448 B
  __shared__ float vals2[16 * 66];                              // 4224 B

  const int tid   = threadIdx.x;            // 0..255
  const int lane  = tid & 63;
  const int wv    = tid >> 6;               // 0..3 = col-wave = kg
  const int col_l = lane & 15;
  const int quad  = lane >> 4;
  const int r0    = (int)blockIdx.x * 16;

  // ---- convert X = [bf16(y), bf16(y^2)] into sX: 512 granules, 2/thread ----
  {
#pragma unroll
    for (int j = 0; j < 2; ++j) {
      const int idx = tid + j * 256;        // granule 0..511
      const int row = idx >> 5, g = idx & 31;
      const float4* ya = (const float4*)y + (size_t)(r0 + row) * 32 + (g & 15) * 2;
      float4 a = ya[0], b = ya[1];
      if (g >= 16) {
        a.x *= a.x; a.y *= a.y; a.z *= a.z; a.w *= a.w;
        b.x *= b.x; b.y *= b.y; b.z *= b.z; b.w *= b.w;
      }
      union { unsigned short us[8]; uint4 v; } o;
      o.us[0] = f2bf(a.x); o.us[1] = f2bf(a.y); o.us[2] = f2bf(a.z); o.us[3] = f2bf(a.w);
      o.us[4] = f2bf(b.x); o.us[5] = f2bf(b.y); o.us[6] = f2bf(b.z); o.us[7] = f2bf(b.w);
      *(uint4*)(sX + row * XSTR + g * 8) = o.v;
    }
  }

  // per-k constant (global, independent of LDS) — hoisted before the barrier
  const float cv = ws[WS_C0F + wv * 16 + col_l];

  __syncthreads();   // X conversion complete; only barrier before epilogue

  // wave's base pointer into its kg's T region, per-lane fragment offset
  const unsigned short* Tb = (const unsigned short*)ws
      + (size_t)wv * 20480 + col_l * 32 + quad * 8;

  // A fragments for all 8 chunks (y: c=0..3, y^2: c=4..7)
  bf16x8 a[8];
#pragma unroll
  for (int c = 0; c < 8; ++c)
    a[c] = *(const bf16x8*)(sX + col_l * XSTR + c * 32 + quad * 8);

  f32x4 acc[9];
#pragma unroll
  for (int f = 0; f < 9; ++f) { acc[f][0] = 0.f; acc[f][1] = 0.f; acc[f][2] = 0.f; acc[f][3] = 0.f; }

  // y^2 diag tiles — issue these loads early, consume at the end
  bf16x8 bq[4];
#pragma unroll
  for (int c = 0; c < 4; ++c)
    bq[c] = *(const bf16x8*)(Tb + (size_t)(36 + c) * 512);

  // main loop: 36 coalesced 1KB loads + 36 MFMAs, no barriers, full unroll
#pragma unroll
  for (int c = 0; c < 4; ++c) {
    bf16x8 b[9];
#pragma unroll
    for (int f = 0; f < 9; ++f)
      b[f] = *(const bf16x8*)(Tb + (size_t)(c * 9 + f) * 512);
#pragma unroll
    for (int f = 0; f < 9; ++f)
      acc[f] = __builtin_amdgcn_mfma_f32_16x16x32_bf16(a[c], b[f], acc[f], 0, 0, 0);
  }
  // diag term: y^2 chunks contribute only to acc[8]
#pragma unroll
  for (int c = 0; c < 4; ++c)
    acc[8] = __builtin_amdgcn_mfma_f32_16x16x32_bf16(a[4 + c], bq[c], acc[8], 0, 0, 0);

  // ---- epilogue: per-k logits in registers ----
  // thread owns k = wv*16 + col_l, rows quad*4 + reg
#pragma unroll
  for (int reg = 0; reg < 4; ++reg) {
    float v = acc[8][reg];                  // linear + diag term
#pragma unroll
    for (int cc = 0; cc < 8; ++cc) v += acc[cc][reg] * acc[cc][reg];
    vals2[(quad * 4 + reg) * 66 + wv * 16 + col_l] = cv + v;
  }
  __syncthreads();

  // per-row 64-k logsumexp: wave wv handles rows wv*4..wv*4+3, lane = k
#pragma unroll
  for (int rr = 0; rr < 4; ++rr) {
    const int row = wv * 4 + rr;
    const float val = vals2[row * 66 + lane];
    float mx = val;
#pragma unroll
    for (int off = 1; off < 64; off <<= 1)
      mx = fmaxf(mx, __shfl_xor(mx, off, 64));
    float ex = expf(val - mx);
#pragma unroll
    for (int off = 1; off < 64; off <<= 1)
      ex += __shfl_xor(ex, off, 64);
    if (lane == 0) out[r0 + row] = mx + logf(ex);
  }
}

extern "C" void kernel_launch(void* const* d_in, const int* in_sizes, int n_in,
                              void* d_out, int out_size, void* d_ws, size_t ws_size,
                              hipStream_t stream) {
  const float* y     = (const float*)d_in[0];
  const float* m     = (const float*)d_in[1];
  const float* delta = (const float*)d_in[2];
  const float* U     = (const float*)d_in[3];
  const float* lar   = (const float*)d_in[4];
  float* out = (float*)d_out;
  float* ws  = (float*)d_ws;

  precomp_kernel<<<K_DIM, 128, 0, stream>>>(m, delta, U, lar, ws);
  logz_full<<<B_DIM / 16, 256, 0, stream>>>(y, ws, out);
}